// Round 11
// baseline (180.529 us; speedup 1.0000x reference)
//
#include <hip/hip_runtime.h>
#include <cstdint>
#include <cstddef>

// ---------- types ----------
typedef __bf16 bf16;
typedef __bf16 bf16x8 __attribute__((ext_vector_type(8)));
typedef __bf16 bf16x2 __attribute__((ext_vector_type(2)));
typedef float  floatx4 __attribute__((ext_vector_type(4)));

typedef __attribute__((address_space(1))) void gvoid_t;
typedef __attribute__((address_space(3))) void lvoid_t;

#define MFMA16(a, b, c) __builtin_amdgcn_mfma_f32_16x16x32_bf16((a), (b), (c), 0, 0, 0)

#if __has_builtin(__builtin_amdgcn_exp2f)
#define EXP2(x) __builtin_amdgcn_exp2f(x)
#else
#define EXP2(x) exp2f(x)
#endif

// B=2, S=2048, D=1024, H=16, DH=64; tokens NT=4096; E3=3072
#define S_TOK 2048
#define E3 3072
#define DMODEL 1024

// ---------- fused fp32 -> bf16 convert (X, Wqkv w/ Q-scale, Wout) ----------
#define NX 4194304
#define NWQ 3145728
#define NWO 1048576
__global__ __launch_bounds__(256) void cvt_all(const float* __restrict__ X,
                                               const float* __restrict__ Wq,
                                               const float* __restrict__ Wo,
                                               bf16* __restrict__ Xb,
                                               bf16* __restrict__ Wqb,
                                               bf16* __restrict__ Wob) {
  int i = (blockIdx.x * 256 + threadIdx.x) * 8;
  const float* s;
  bf16* d;
  float sc = 1.0f;
  int off;
  if (i < NX) {
    s = X; d = Xb; off = i;
  } else if (i < NX + NWQ) {
    off = i - NX; s = Wq; d = Wqb;
    int row = off >> 10;  // D=1024 per row; rows with e%192<64 produce Q
    if ((row % 192) < 64) sc = 0.18033688011f;  // 0.125*log2(e) pre-folded
  } else {
    off = i - NX - NWQ; s = Wo; d = Wob;
  }
  const float4* p = (const float4*)(s + off);
  float4 a = p[0], b = p[1];
  bf16x8 o;
  o[0] = (bf16)(a.x * sc); o[1] = (bf16)(a.y * sc);
  o[2] = (bf16)(a.z * sc); o[3] = (bf16)(a.w * sc);
  o[4] = (bf16)(b.x * sc); o[5] = (bf16)(b.y * sc);
  o[6] = (bf16)(b.z * sc); o[7] = (bf16)(b.w * sc);
  *(bf16x8*)(d + off) = o;
}

// ---------- async global->LDS, 16B per lane ----------
__device__ __forceinline__ void gl_lds16(const bf16* g, bf16* l) {
  __builtin_amdgcn_global_load_lds((gvoid_t*)g, (lvoid_t*)l, 16, 0, 0);
}

// ---------- GEMM: BK=64, XOR-swizzled LDS; optional fused V-transpose ----------
template <bool OUT_BF16, bool FUSE_V>
__global__ __launch_bounds__(256) void gemm_bt(const bf16* __restrict__ A,
                                               const bf16* __restrict__ Bt,
                                               void* __restrict__ Cv,
                                               bf16* __restrict__ Vt,
                                               int M, int N, int K) {
  __shared__ bf16 sA[128 * 64];  // 16 KB
  __shared__ bf16 sB[128 * 64];  // 16 KB
  const int tid = threadIdx.x;
  const int wv = tid >> 6, lane = tid & 63;
  const int wr = wv >> 1, wc = wv & 1;
  const int lrow = lane & 15, lgrp = lane >> 4;
  const int R0 = blockIdx.y * 128, C0 = blockIdx.x * 128;

  floatx4 acc[4][4] = {};

  const int srow = lane >> 3;
  const int schk = (lane & 7) ^ srow;  // source chunk, swizzle key = row&7
  const bf16* gA = A + (size_t)(R0 + wv * 32 + srow) * K + schk * 8;
  const bf16* gB = Bt + (size_t)(C0 + wv * 32 + srow) * K + schk * 8;
  bf16* lA = sA + wv * 32 * 64;
  bf16* lB = sB + wv * 32 * 64;
  const size_t rs8 = (size_t)8 * K;

  for (int k0 = 0; k0 < K; k0 += 64) {
#pragma unroll
    for (int c = 0; c < 4; c++) {
      gl_lds16(gA + k0 + c * rs8, lA + c * 512);
      gl_lds16(gB + k0 + c * rs8, lB + c * 512);
    }
    __syncthreads();
#pragma unroll
    for (int kk = 0; kk < 2; kk++) {
      bf16x8 af[4], bfr[4];
#pragma unroll
      for (int i = 0; i < 4; i++) {
        int r = wr * 64 + i * 16 + lrow;
        af[i] = *(const bf16x8*)&sA[r * 64 + ((kk * 4 + lgrp) ^ (r & 7)) * 8];
      }
#pragma unroll
      for (int j = 0; j < 4; j++) {
        int r = wc * 64 + j * 16 + lrow;
        bfr[j] = *(const bf16x8*)&sB[r * 64 + ((kk * 4 + lgrp) ^ (r & 7)) * 8];
      }
#pragma unroll
      for (int i = 0; i < 4; i++)
#pragma unroll
        for (int j = 0; j < 4; j++)
          acc[i][j] = MFMA16(af[i], bfr[j], acc[i][j]);
    }
    __syncthreads();
  }

  const int rbase = R0 + wr * 64 + lgrp * 4;
  const int cbase = C0 + wc * 64 + lrow;
  if (OUT_BF16) {
    bf16* C = (bf16*)Cv;
#pragma unroll
    for (int i = 0; i < 4; i++)
#pragma unroll
      for (int j = 0; j < 4; j++) {
        const int col = cbase + j * 16;
        const int m192 = col % 192;
        const int hh = col / 192;
#pragma unroll
        for (int r = 0; r < 4; r++) {
          const int row = rbase + i * 16 + r;
          bf16 val = (bf16)acc[i][j][r];
          bf16* dst;
          if (FUSE_V && m192 >= 128) {
            const int sl = row & 2047;
            const int sp = (sl & ~31) | ((sl & 15) << 1) | ((sl >> 4) & 1);
            dst = Vt + ((size_t)(((row >> 11) * 16 + hh) * 64 + (m192 - 128))) * S_TOK + sp;
          } else {
            dst = C + (size_t)row * N + col;
          }
          *dst = val;
        }
      }
  } else {
    float* C = (float*)Cv;
#pragma unroll
    for (int i = 0; i < 4; i++)
#pragma unroll
      for (int j = 0; j < 4; j++)
#pragma unroll
        for (int r = 0; r < 4; r++)
          C[(size_t)(rbase + i * 16 + r) * N + cbase + j * 16] = acc[i][j][r];
  }
}

// ---------- GEMM 128x64 tile (out-proj: N=1024 -> 512 blocks, 2/CU) ----------
__global__ __launch_bounds__(256) void gemm_bt_n64(const bf16* __restrict__ A,
                                                   const bf16* __restrict__ Bt,
                                                   float* __restrict__ C,
                                                   int M, int N, int K) {
  __shared__ bf16 sA[128 * 64];  // 16 KB
  __shared__ bf16 sB[64 * 64];   //  8 KB
  const int tid = threadIdx.x;
  const int wv = tid >> 6, lane = tid & 63;
  const int wr = wv >> 1, wc = wv & 1;
  const int lrow = lane & 15, lgrp = lane >> 4;
  const int R0 = blockIdx.y * 128, C0 = blockIdx.x * 64;

  floatx4 acc[4][2] = {};

  const int srow = lane >> 3;
  const int schk = (lane & 7) ^ srow;
  const bf16* gA = A + (size_t)(R0 + wv * 32 + srow) * K + schk * 8;
  const bf16* gB = Bt + (size_t)(C0 + wv * 16 + srow) * K + schk * 8;
  bf16* lA = sA + wv * 32 * 64;
  bf16* lB = sB + wv * 16 * 64;
  const size_t rs8 = (size_t)8 * K;

  for (int k0 = 0; k0 < K; k0 += 64) {
#pragma unroll
    for (int c = 0; c < 4; c++) gl_lds16(gA + k0 + c * rs8, lA + c * 512);
#pragma unroll
    for (int c = 0; c < 2; c++) gl_lds16(gB + k0 + c * rs8, lB + c * 512);
    __syncthreads();
#pragma unroll
    for (int kk = 0; kk < 2; kk++) {
      bf16x8 af[4], bfr[2];
#pragma unroll
      for (int i = 0; i < 4; i++) {
        int r = wr * 64 + i * 16 + lrow;
        af[i] = *(const bf16x8*)&sA[r * 64 + ((kk * 4 + lgrp) ^ (r & 7)) * 8];
      }
#pragma unroll
      for (int j = 0; j < 2; j++) {
        int r = wc * 32 + j * 16 + lrow;
        bfr[j] = *(const bf16x8*)&sB[r * 64 + ((kk * 4 + lgrp) ^ (r & 7)) * 8];
      }
#pragma unroll
      for (int i = 0; i < 4; i++)
#pragma unroll
        for (int j = 0; j < 2; j++)
          acc[i][j] = MFMA16(af[i], bfr[j], acc[i][j]);
    }
    __syncthreads();
  }

  const int rbase = R0 + wr * 64 + lgrp * 4;
  const int cbase = C0 + wc * 32 + lrow;
#pragma unroll
  for (int i = 0; i < 4; i++)
#pragma unroll
    for (int j = 0; j < 2; j++)
#pragma unroll
      for (int r = 0; r < 4; r++)
        C[(size_t)(rbase + i * 16 + r) * N + cbase + j * 16] = acc[i][j][r];
}

// ---------- attention v9: 128-key stages (half the barriers of v8) ----------
// Block = 512 thr (8 waves), wave owns 16 q-rows, sees all 2048 keys.
// Stage = 128 keys, double-buffered: 16 stages -> 16 barrier intervals (v8: 32).
// LDS 74.25 KB -> still 2 blocks/CU = 16 waves/CU. Per thread per stage:
// 2 K + 2 V gl_lds16. XOR source swizzles: K 8-chunk keyed row&7; V 16-chunk
// keyed d&15 (read chunk (g*4+lgrp)^lrow -> each 4-bank group serves exactly
// 8 lanes = structural minimum, conflict-free).
__global__ __launch_bounds__(512, 4) void attn(const bf16* __restrict__ qkv,
                                               const bf16* __restrict__ Vt,
                                               bf16* __restrict__ vals) {
  __shared__ bf16 sK[2][128 * 64];  // 32 KB [buf][key][dh]
  __shared__ bf16 sV[2][64 * 128];  // 32 KB [buf][d][key']
  __shared__ bf16 sP[8 * 640];      // 10.25 KB wave-private P round-trip

  const int tid = threadIdx.x;
  const int wv = tid >> 6, lane = tid & 63;
  const int lrow = lane & 15, lgrp = lane >> 4;
  const int b = blockIdx.z, h = blockIdx.y;
  const int qb = blockIdx.x * 128;

  // K staging: wave w covers key-rows [w*8,w*8+8) and [64+w*8, ...+8)
  const int srow = lane >> 3;          // 0..7
  const int scol = (lane & 7) ^ srow;  // 8-chunk swizzle, key = row&7 = srow
  const bf16* kg0 = qkv + (size_t)(b * S_TOK + wv * 8 + srow) * E3 + h * 192 + 64 + scol * 8;
  // V staging: wave w covers d-rows [w*8,w*8+8) as 2 calls of 4 rows
  const int vrow = lane >> 4;          // 0..3
  const int vchk = lane & 15;          // dest chunk (16-chunk rows)
  const int d0 = wv * 8 + vrow, d1 = d0 + 4;
  const bf16* vg0 = Vt + (size_t)((b * 16 + h) * 64 + d0) * S_TOK + (vchk ^ (d0 & 15)) * 8;
  const bf16* vg1 = Vt + (size_t)((b * 16 + h) * 64 + d1) * S_TOK + (vchk ^ (d1 & 15)) * 8;

  // Q A-fragments (pre-scaled by 0.125*log2e): A[m=lane&15][k=lgrp*8+j]
  const bf16* qp = qkv + (size_t)(b * S_TOK + qb + wv * 16) * E3 + h * 192;
  bf16x8 qa[2];
#pragma unroll
  for (int dh = 0; dh < 2; dh++)
    qa[dh] = *(const bf16x8*)(qp + (size_t)lrow * E3 + dh * 32 + lgrp * 8);

  floatx4 O[4] = {};
  floatx4 lacc = {};
  bf16x8 ones;
  const bf16 one1 = (bf16)1.0f;
#pragma unroll
  for (int j = 0; j < 8; j++) ones[j] = one1;

  bf16* sPw = sP + wv * 640;

  auto stage = [&](int buf, int st) {
    const bf16* kg = kg0 + (size_t)st * 128 * E3;
    gl_lds16(kg, &sK[buf][wv * 512]);
    gl_lds16(kg + (size_t)64 * E3, &sK[buf][4096 + wv * 512]);
    gl_lds16(vg0 + st * 128, &sV[buf][wv * 1024]);
    gl_lds16(vg1 + st * 128, &sV[buf][wv * 1024 + 512]);
  };

  auto compute = [&](int buf) {
#pragma unroll
    for (int g = 0; g < 4; g++) {  // four 32-key groups of the 128-key stage
      bf16x8 kf[2][2];
#pragma unroll
      for (int t = 0; t < 2; t++)
#pragma unroll
        for (int dh = 0; dh < 2; dh++)
          kf[t][dh] = *(const bf16x8*)&sK[buf][(g * 32 + t * 16 + lrow) * 64 +
                                              ((dh * 4 + lgrp) ^ (lrow & 7)) * 8];
      floatx4 sc0 = {0.f, 0.f, 0.f, 0.f}, sc1 = {0.f, 0.f, 0.f, 0.f};
      sc0 = MFMA16(qa[0], kf[0][0], sc0);
      sc0 = MFMA16(qa[1], kf[0][1], sc0);
      sc1 = MFMA16(qa[0], kf[1][0], sc1);
      sc1 = MFMA16(qa[1], kf[1][1], sc1);
#pragma unroll
      for (int r = 0; r < 4; r++) {
        bf16x2 h2;
        h2[0] = (bf16)EXP2(sc0[r]);
        h2[1] = (bf16)EXP2(sc1[r]);
        *(unsigned*)&sPw[(lgrp * 4 + r) * 40 + lrow * 2] =
            __builtin_bit_cast(unsigned, h2);
      }
      bf16x8 vf[4];
#pragma unroll
      for (int dt = 0; dt < 4; dt++)
        vf[dt] = *(const bf16x8*)&sV[buf][(dt * 16 + lrow) * 128 +
                                          ((g * 4 + lgrp) ^ lrow) * 8];
      bf16x8 pf = *(const bf16x8*)&sPw[lrow * 40 + lgrp * 8];
#pragma unroll
      for (int dt = 0; dt < 4; dt++) O[dt] = MFMA16(pf, vf[dt], O[dt]);
      lacc = MFMA16(pf, ones, lacc);
    }
  };

  stage(0, 0);
  __syncthreads();
#pragma unroll 1
  for (int st = 0; st < 16; st += 2) {
    stage(1, st + 1);
    compute(0);
    __syncthreads();
    if (st + 2 < 16) stage(0, st + 2);
    compute(1);
    __syncthreads();
  }

  bf16* vout = vals + (size_t)(b * S_TOK + qb + wv * 16) * DMODEL + h * 64;
#pragma unroll
  for (int r = 0; r < 4; r++) {
    float rinv = __builtin_amdgcn_rcpf(lacc[r]);
#pragma unroll
    for (int dt = 0; dt < 4; dt++)
      vout[(size_t)(lgrp * 4 + r) * DMODEL + dt * 16 + lrow] =
          (bf16)(O[dt][r] * rinv);
  }
}

// ---------- host ----------
extern "C" void kernel_launch(void* const* d_in, const int* in_sizes, int n_in,
                              void* d_out, int out_size, void* d_ws, size_t ws_size,
                              hipStream_t stream) {
  const float* X = (const float*)d_in[0];     // (2,2048,1024)
  const float* Wqkv = (const float*)d_in[1];  // (3072,1024)
  const float* Wout = (const float*)d_in[2];  // (1024,1024)
  float* out = (float*)d_out;                 // (2,2048,1024)

  char* ws = (char*)d_ws;
  bf16* Xb = (bf16*)(ws);                          //  8 MB
  bf16* Wqb = (bf16*)(ws + ((size_t)8 << 20));     //  6 MB
  bf16* Wob = (bf16*)(ws + ((size_t)14 << 20));    //  2 MB
  bf16* qkvb = (bf16*)(ws + ((size_t)16 << 20));   // 24 MB (4096 x 3072; V-part unused)
  bf16* Vt = (bf16*)(ws + ((size_t)40 << 20));     //  8 MB (2*16*64 x 2048)
  bf16* vals = (bf16*)(ws + ((size_t)48 << 20));   //  8 MB (4096 x 1024)

  cvt_all<<<(NX + NWQ + NWO) / 2048, 256, 0, stream>>>(X, Wqkv, Wout, Xb, Wqb, Wob);

  // qkv = X @ Wqkv^T, V-part written straight to Vt (sigma-permuted)
  gemm_bt<true, true><<<dim3(24, 32), 256, 0, stream>>>(Xb, Wqb, qkvb, Vt, 4096, 3072, 1024);

  attn<<<dim3(16, 16, 2), 512, 0, stream>>>(qkvb, Vt, vals);

  // out = vals @ Wout^T : 128x64 tiles -> 512 blocks (2/CU)
  gemm_bt_n64<<<dim3(16, 32), 256, 0, stream>>>(vals, Wob, out, 4096, 1024, 1024);
}

// Round 12
// 177.533 us; speedup vs baseline: 1.0169x; 1.0169x over previous
//
#include <hip/hip_runtime.h>
#include <cstdint>
#include <cstddef>

// ---------- types ----------
typedef __bf16 bf16;
typedef __bf16 bf16x8 __attribute__((ext_vector_type(8)));
typedef __bf16 bf16x2 __attribute__((ext_vector_type(2)));
typedef float  floatx4 __attribute__((ext_vector_type(4)));

typedef __attribute__((address_space(1))) void gvoid_t;
typedef __attribute__((address_space(3))) void lvoid_t;

#define MFMA16(a, b, c) __builtin_amdgcn_mfma_f32_16x16x32_bf16((a), (b), (c), 0, 0, 0)

#if __has_builtin(__builtin_amdgcn_exp2f)
#define EXP2(x) __builtin_amdgcn_exp2f(x)
#else
#define EXP2(x) exp2f(x)
#endif

// B=2, S=2048, D=1024, H=16, DH=64; tokens NT=4096; E3=3072
#define S_TOK 2048
#define E3 3072
#define DMODEL 1024

// ---------- fused fp32 -> bf16 convert (X, Wqkv w/ Q-scale, Wout) ----------
#define NX 4194304
#define NWQ 3145728
#define NWO 1048576
__global__ __launch_bounds__(256) void cvt_all(const float* __restrict__ X,
                                               const float* __restrict__ Wq,
                                               const float* __restrict__ Wo,
                                               bf16* __restrict__ Xb,
                                               bf16* __restrict__ Wqb,
                                               bf16* __restrict__ Wob) {
  int i = (blockIdx.x * 256 + threadIdx.x) * 8;
  const float* s;
  bf16* d;
  float sc = 1.0f;
  int off;
  if (i < NX) {
    s = X; d = Xb; off = i;
  } else if (i < NX + NWQ) {
    off = i - NX; s = Wq; d = Wqb;
    int row = off >> 10;  // D=1024 per row; rows with e%192<64 produce Q
    if ((row % 192) < 64) sc = 0.18033688011f;  // 0.125*log2(e) pre-folded
  } else {
    off = i - NX - NWQ; s = Wo; d = Wob;
  }
  const float4* p = (const float4*)(s + off);
  float4 a = p[0], b = p[1];
  bf16x8 o;
  o[0] = (bf16)(a.x * sc); o[1] = (bf16)(a.y * sc);
  o[2] = (bf16)(a.z * sc); o[3] = (bf16)(a.w * sc);
  o[4] = (bf16)(b.x * sc); o[5] = (bf16)(b.y * sc);
  o[6] = (bf16)(b.z * sc); o[7] = (bf16)(b.w * sc);
  *(bf16x8*)(d + off) = o;
}

// ---------- async global->LDS, 16B per lane ----------
__device__ __forceinline__ void gl_lds16(const bf16* g, bf16* l) {
  __builtin_amdgcn_global_load_lds((gvoid_t*)g, (lvoid_t*)l, 16, 0, 0);
}

// ---------- GEMM: BK=64, XOR-swizzled LDS; optional fused V-transpose ----------
template <bool OUT_BF16, bool FUSE_V>
__global__ __launch_bounds__(256) void gemm_bt(const bf16* __restrict__ A,
                                               const bf16* __restrict__ Bt,
                                               void* __restrict__ Cv,
                                               bf16* __restrict__ Vt,
                                               int M, int N, int K) {
  __shared__ bf16 sA[128 * 64];  // 16 KB
  __shared__ bf16 sB[128 * 64];  // 16 KB
  const int tid = threadIdx.x;
  const int wv = tid >> 6, lane = tid & 63;
  const int wr = wv >> 1, wc = wv & 1;
  const int lrow = lane & 15, lgrp = lane >> 4;
  const int R0 = blockIdx.y * 128, C0 = blockIdx.x * 128;

  floatx4 acc[4][4] = {};

  const int srow = lane >> 3;
  const int schk = (lane & 7) ^ srow;  // source chunk, swizzle key = row&7
  const bf16* gA = A + (size_t)(R0 + wv * 32 + srow) * K + schk * 8;
  const bf16* gB = Bt + (size_t)(C0 + wv * 32 + srow) * K + schk * 8;
  bf16* lA = sA + wv * 32 * 64;
  bf16* lB = sB + wv * 32 * 64;
  const size_t rs8 = (size_t)8 * K;

  for (int k0 = 0; k0 < K; k0 += 64) {
#pragma unroll
    for (int c = 0; c < 4; c++) {
      gl_lds16(gA + k0 + c * rs8, lA + c * 512);
      gl_lds16(gB + k0 + c * rs8, lB + c * 512);
    }
    __syncthreads();
#pragma unroll
    for (int kk = 0; kk < 2; kk++) {
      bf16x8 af[4], bfr[4];
#pragma unroll
      for (int i = 0; i < 4; i++) {
        int r = wr * 64 + i * 16 + lrow;
        af[i] = *(const bf16x8*)&sA[r * 64 + ((kk * 4 + lgrp) ^ (r & 7)) * 8];
      }
#pragma unroll
      for (int j = 0; j < 4; j++) {
        int r = wc * 64 + j * 16 + lrow;
        bfr[j] = *(const bf16x8*)&sB[r * 64 + ((kk * 4 + lgrp) ^ (r & 7)) * 8];
      }
#pragma unroll
      for (int i = 0; i < 4; i++)
#pragma unroll
        for (int j = 0; j < 4; j++)
          acc[i][j] = MFMA16(af[i], bfr[j], acc[i][j]);
    }
    __syncthreads();
  }

  const int rbase = R0 + wr * 64 + lgrp * 4;
  const int cbase = C0 + wc * 64 + lrow;
  if (OUT_BF16) {
    bf16* C = (bf16*)Cv;
#pragma unroll
    for (int i = 0; i < 4; i++)
#pragma unroll
      for (int j = 0; j < 4; j++) {
        const int col = cbase + j * 16;
        const int m192 = col % 192;
        const int hh = col / 192;
#pragma unroll
        for (int r = 0; r < 4; r++) {
          const int row = rbase + i * 16 + r;
          bf16 val = (bf16)acc[i][j][r];
          bf16* dst;
          if (FUSE_V && m192 >= 128) {
            const int sl = row & 2047;
            const int sp = (sl & ~31) | ((sl & 15) << 1) | ((sl >> 4) & 1);
            dst = Vt + ((size_t)(((row >> 11) * 16 + hh) * 64 + (m192 - 128))) * S_TOK + sp;
          } else {
            dst = C + (size_t)row * N + col;
          }
          *dst = val;
        }
      }
  } else {
    float* C = (float*)Cv;
#pragma unroll
    for (int i = 0; i < 4; i++)
#pragma unroll
      for (int j = 0; j < 4; j++)
#pragma unroll
        for (int r = 0; r < 4; r++)
          C[(size_t)(rbase + i * 16 + r) * N + cbase + j * 16] = acc[i][j][r];
  }
}

// ---------- GEMM 128x64 tile (out-proj: N=1024 -> 512 blocks, 2/CU) ----------
__global__ __launch_bounds__(256) void gemm_bt_n64(const bf16* __restrict__ A,
                                                   const bf16* __restrict__ Bt,
                                                   float* __restrict__ C,
                                                   int M, int N, int K) {
  __shared__ bf16 sA[128 * 64];  // 16 KB
  __shared__ bf16 sB[64 * 64];   //  8 KB
  const int tid = threadIdx.x;
  const int wv = tid >> 6, lane = tid & 63;
  const int wr = wv >> 1, wc = wv & 1;
  const int lrow = lane & 15, lgrp = lane >> 4;
  const int R0 = blockIdx.y * 128, C0 = blockIdx.x * 64;

  floatx4 acc[4][2] = {};

  const int srow = lane >> 3;
  const int schk = (lane & 7) ^ srow;
  const bf16* gA = A + (size_t)(R0 + wv * 32 + srow) * K + schk * 8;
  const bf16* gB = Bt + (size_t)(C0 + wv * 16 + srow) * K + schk * 8;
  bf16* lA = sA + wv * 32 * 64;
  bf16* lB = sB + wv * 16 * 64;
  const size_t rs8 = (size_t)8 * K;

  for (int k0 = 0; k0 < K; k0 += 64) {
#pragma unroll
    for (int c = 0; c < 4; c++) gl_lds16(gA + k0 + c * rs8, lA + c * 512);
#pragma unroll
    for (int c = 0; c < 2; c++) gl_lds16(gB + k0 + c * rs8, lB + c * 512);
    __syncthreads();
#pragma unroll
    for (int kk = 0; kk < 2; kk++) {
      bf16x8 af[4], bfr[2];
#pragma unroll
      for (int i = 0; i < 4; i++) {
        int r = wr * 64 + i * 16 + lrow;
        af[i] = *(const bf16x8*)&sA[r * 64 + ((kk * 4 + lgrp) ^ (r & 7)) * 8];
      }
#pragma unroll
      for (int j = 0; j < 2; j++) {
        int r = wc * 32 + j * 16 + lrow;
        bfr[j] = *(const bf16x8*)&sB[r * 64 + ((kk * 4 + lgrp) ^ (r & 7)) * 8];
      }
#pragma unroll
      for (int i = 0; i < 4; i++)
#pragma unroll
        for (int j = 0; j < 2; j++)
          acc[i][j] = MFMA16(af[i], bfr[j], acc[i][j]);
    }
    __syncthreads();
  }

  const int rbase = R0 + wr * 64 + lgrp * 4;
  const int cbase = C0 + wc * 32 + lrow;
#pragma unroll
  for (int i = 0; i < 4; i++)
#pragma unroll
    for (int j = 0; j < 2; j++)
#pragma unroll
      for (int r = 0; r < 4; r++)
        C[(size_t)(rbase + i * 16 + r) * N + cbase + j * 16] = acc[i][j][r];
}

// ---------- attention v10: 32 q-rows/wave — halve LDS reads per unit work ----------
// R11 arithmetic: 16 waves/CU x 36 ds_read_b128/stage x 12cyc = 6.9k cyc/stage
// = 46us over 16 stages == measured 50us -> LDS-READ-BW bound. Fix: each wave
// owns TWO 16-row tiles (32 q-rows), so kf/vf fragment reads serve 2x the MFMA:
// per group 10 b128 (4K+4V+2P) for 18 MFMA vs 9 for 9. Block = 8 waves =
// 256 q-rows; grid 256 blocks (1/CU, 8 waves/CU). Model: 8 x 40 x 12 = 3.8k
// cyc/stage -> ~26us floor. (512,2): 256-reg budget for the ~120-reg live set.
__global__ __launch_bounds__(512, 2) void attn(const bf16* __restrict__ qkv,
                                               const bf16* __restrict__ Vt,
                                               bf16* __restrict__ vals) {
  __shared__ bf16 sK[2][128 * 64];  // 32 KB [buf][key][dh]
  __shared__ bf16 sV[2][64 * 128];  // 32 KB [buf][d][key']
  __shared__ bf16 sP[8][2][640];    // 20.5 KB [wave][rowtile] P round-trip

  const int tid = threadIdx.x;
  const int wv = tid >> 6, lane = tid & 63;
  const int lrow = lane & 15, lgrp = lane >> 4;
  const int b = blockIdx.z, h = blockIdx.y;
  const int qb = blockIdx.x * 256;

  // K staging: wave w covers key-rows [w*8,w*8+8) and [64+w*8, ...+8)
  const int srow = lane >> 3;          // 0..7
  const int scol = (lane & 7) ^ srow;  // 8-chunk swizzle, key = row&7 = srow
  const bf16* kg0 = qkv + (size_t)(b * S_TOK + wv * 8 + srow) * E3 + h * 192 + 64 + scol * 8;
  // V staging: wave w covers d-rows [w*8,w*8+8) as 2 calls of 4 rows
  const int vrow = lane >> 4;          // 0..3
  const int vchk = lane & 15;          // dest chunk (16-chunk rows)
  const int d0 = wv * 8 + vrow, d1 = d0 + 4;
  const bf16* vg0 = Vt + (size_t)((b * 16 + h) * 64 + d0) * S_TOK + (vchk ^ (d0 & 15)) * 8;
  const bf16* vg1 = Vt + (size_t)((b * 16 + h) * 64 + d1) * S_TOK + (vchk ^ (d1 & 15)) * 8;

  // Q A-fragments for two row-tiles (pre-scaled): A[m=lane&15][k=lgrp*8+j]
  const bf16* qp = qkv + (size_t)(b * S_TOK + qb + wv * 32) * E3 + h * 192;
  bf16x8 qa[2][2];
#pragma unroll
  for (int rt = 0; rt < 2; rt++)
#pragma unroll
    for (int dh = 0; dh < 2; dh++)
      qa[rt][dh] = *(const bf16x8*)(qp + (size_t)(rt * 16 + lrow) * E3 + dh * 32 + lgrp * 8);

  floatx4 O[2][4] = {};
  floatx4 lacc[2] = {};
  bf16x8 ones;
  const bf16 one1 = (bf16)1.0f;
#pragma unroll
  for (int j = 0; j < 8; j++) ones[j] = one1;

  auto stage = [&](int buf, int st) {
    const bf16* kg = kg0 + (size_t)st * 128 * E3;
    gl_lds16(kg, &sK[buf][wv * 512]);
    gl_lds16(kg + (size_t)64 * E3, &sK[buf][4096 + wv * 512]);
    gl_lds16(vg0 + st * 128, &sV[buf][wv * 1024]);
    gl_lds16(vg1 + st * 128, &sV[buf][wv * 1024 + 512]);
  };

  auto compute = [&](int buf) {
#pragma unroll
    for (int g = 0; g < 4; g++) {  // four 32-key groups of the 128-key stage
      bf16x8 kf[2][2];
#pragma unroll
      for (int t = 0; t < 2; t++)
#pragma unroll
        for (int dh = 0; dh < 2; dh++)
          kf[t][dh] = *(const bf16x8*)&sK[buf][(g * 32 + t * 16 + lrow) * 64 +
                                              ((dh * 4 + lgrp) ^ (lrow & 7)) * 8];
#pragma unroll
      for (int rt = 0; rt < 2; rt++) {
        floatx4 sc0 = {0.f, 0.f, 0.f, 0.f}, sc1 = {0.f, 0.f, 0.f, 0.f};
        sc0 = MFMA16(qa[rt][0], kf[0][0], sc0);
        sc0 = MFMA16(qa[rt][1], kf[0][1], sc0);
        sc1 = MFMA16(qa[rt][0], kf[1][0], sc1);
        sc1 = MFMA16(qa[rt][1], kf[1][1], sc1);
#pragma unroll
        for (int r = 0; r < 4; r++) {
          bf16x2 h2;
          h2[0] = (bf16)EXP2(sc0[r]);
          h2[1] = (bf16)EXP2(sc1[r]);
          *(unsigned*)&sP[wv][rt][(lgrp * 4 + r) * 40 + lrow * 2] =
              __builtin_bit_cast(unsigned, h2);
        }
      }
      bf16x8 vf[4];
#pragma unroll
      for (int dt = 0; dt < 4; dt++)
        vf[dt] = *(const bf16x8*)&sV[buf][(dt * 16 + lrow) * 128 +
                                          ((g * 4 + lgrp) ^ lrow) * 8];
#pragma unroll
      for (int rt = 0; rt < 2; rt++) {
        bf16x8 pf = *(const bf16x8*)&sP[wv][rt][lrow * 40 + lgrp * 8];
#pragma unroll
        for (int dt = 0; dt < 4; dt++) O[rt][dt] = MFMA16(pf, vf[dt], O[rt][dt]);
        lacc[rt] = MFMA16(pf, ones, lacc[rt]);
      }
    }
  };

  stage(0, 0);
  __syncthreads();
#pragma unroll 1
  for (int st = 0; st < 16; st += 2) {
    stage(1, st + 1);
    compute(0);
    __syncthreads();
    if (st + 2 < 16) stage(0, st + 2);
    compute(1);
    __syncthreads();
  }

  bf16* vout = vals + (size_t)(b * S_TOK + qb + wv * 32) * DMODEL + h * 64;
#pragma unroll
  for (int rt = 0; rt < 2; rt++)
#pragma unroll
    for (int r = 0; r < 4; r++) {
      float rinv = __builtin_amdgcn_rcpf(lacc[rt][r]);
#pragma unroll
      for (int dt = 0; dt < 4; dt++)
        vout[(size_t)(rt * 16 + lgrp * 4 + r) * DMODEL + dt * 16 + lrow] =
            (bf16)(O[rt][dt][r] * rinv);
    }
}

// ---------- host ----------
extern "C" void kernel_launch(void* const* d_in, const int* in_sizes, int n_in,
                              void* d_out, int out_size, void* d_ws, size_t ws_size,
                              hipStream_t stream) {
  const float* X = (const float*)d_in[0];     // (2,2048,1024)
  const float* Wqkv = (const float*)d_in[1];  // (3072,1024)
  const float* Wout = (const float*)d_in[2];  // (1024,1024)
  float* out = (float*)d_out;                 // (2,2048,1024)

  char* ws = (char*)d_ws;
  bf16* Xb = (bf16*)(ws);                          //  8 MB
  bf16* Wqb = (bf16*)(ws + ((size_t)8 << 20));     //  6 MB
  bf16* Wob = (bf16*)(ws + ((size_t)14 << 20));    //  2 MB
  bf16* qkvb = (bf16*)(ws + ((size_t)16 << 20));   // 24 MB (4096 x 3072; V-part unused)
  bf16* Vt = (bf16*)(ws + ((size_t)40 << 20));     //  8 MB (2*16*64 x 2048)
  bf16* vals = (bf16*)(ws + ((size_t)48 << 20));   //  8 MB (4096 x 1024)

  cvt_all<<<(NX + NWQ + NWO) / 2048, 256, 0, stream>>>(X, Wqkv, Wout, Xb, Wqb, Wob);

  // qkv = X @ Wqkv^T, V-part written straight to Vt (sigma-permuted)
  gemm_bt<true, true><<<dim3(24, 32), 256, 0, stream>>>(Xb, Wqb, qkvb, Vt, 4096, 3072, 1024);

  attn<<<dim3(8, 16, 2), 512, 0, stream>>>(qkvb, Vt, vals);

  // out = vals @ Wout^T : 128x64 tiles -> 512 blocks (2/CU)
  gemm_bt_n64<<<dim3(16, 32), 256, 0, stream>>>(vals, Wob, out, 4096, 1024, 1024);
}